// Round 7
// baseline (397.348 us; speedup 1.0000x reference)
//
#include <hip/hip_runtime.h>

// Problem constants (match reference)
#define Bdim 4
#define Cdim 32
#define Hdim 512
#define Wdim 512
#define HWdim (Hdim * Wdim)

typedef __attribute__((ext_vector_type(4))) float    f32x4;
typedef __attribute__((ext_vector_type(2))) _Float16 f16x2;
typedef __attribute__((ext_vector_type(4))) _Float16 f16x4;
typedef __attribute__((ext_vector_type(8))) _Float16 f16x8;

// ---------------------------------------------------------------------------
// Kernel A: transpose x [B][C][H][W] (fp32) -> ws NHWC [B][H][W][C] (fp16)
// One block: (b, h) fixed, 128-wide w strip, all 32 c.
// XCD-chunk swizzle aligned with the gather kernel (ws stays in writer's L2).
// ---------------------------------------------------------------------------
__global__ __launch_bounds__(256) void transpose_nhwc_half_kernel(
    const float* __restrict__ x, _Float16* __restrict__ ws)
{
    __shared__ float lds[Cdim * 132];   // 32 x 132 floats = 16896 B

    // 8192 blocks; chunk swizzle: XCD k owns idx [k*1024, (k+1)*1024)
    const int orig = blockIdx.x;
    const int idx  = (orig & 7) * 1024 + (orig >> 3);

    const int tw  = idx & 3;                  // W/128 = 4 strips
    const int h   = (idx >> 2) & (Hdim - 1);
    const int b   = idx >> 11;
    const int w0  = tw * 128;
    const int t   = threadIdx.x;

    // 32c x 128w = 1024 float4s, 4 per thread. Issue all loads first (MLP).
    f32x4 r[4];
    #pragma unroll
    for (int i = 0; i < 4; ++i) {
        const int f4 = i * 256 + t;           // 0..1023
        const int c  = f4 >> 5;               // 32 float4 per row
        const int w4 = f4 & 31;
        r[i] = *(const f32x4*)(x + (((size_t)b * Cdim + c) * Hdim + h) * Wdim + w0 + w4 * 4);
    }
    #pragma unroll
    for (int i = 0; i < 4; ++i) {
        const int f4 = i * 256 + t;
        *(f32x4*)(lds + (f4 >> 5) * 132 + (f4 & 31) * 4) = r[i];
    }
    __syncthreads();

    // output block = 4096 halves contiguous; thread t writes halves [t*16, t*16+16)
    const size_t base = (((size_t)b * Hdim + h) * Wdim + w0) * Cdim;
    const int w_ = t >> 1;                    // local w (0..127)
    const int c0 = (t & 1) * 16;              // first channel (0 or 16)
    f16x8 v0, v1;
    #pragma unroll
    for (int k = 0; k < 8; ++k) v0[k] = (_Float16)lds[(c0 + k) * 132 + w_];
    #pragma unroll
    for (int k = 0; k < 8; ++k) v1[k] = (_Float16)lds[(c0 + 8 + k) * 132 + w_];
    *(f16x8*)(ws + base + (size_t)w_ * Cdim + c0)     = v0;   // 16B store
    *(f16x8*)(ws + base + (size_t)w_ * Cdim + c0 + 8) = v1;   // 16B store
}

// ---------------------------------------------------------------------------
// Kernel B: gather from NHWC fp16 ws + residual -> out (NCHW fp32)
// R7: LANE-OWNS-PIXEL. Block = 256 consecutive pixels of one row; thread t
// owns pixel w0+t end-to-end. Zero __shfl, zero LDS, zero barriers:
//   - flow math -> 4 corner offsets + 4 weights in the lane's own registers
//   - each corner = one 64B NHWC pixel line, read as 4x f16x8 (16B);
//     all lines still fetched exactly once and fully consumed (same L1/L2
//     traffic as the wave-cooperative layout, just per-lane addressing)
//   - acc[32] fp32; result skips the fp16 re-round entirely
//   - residual add + NCHW NT stores: 64 lanes x consecutive pixels = 256B
//     runs per instruction (byte-identical pattern to the proven phase 3)
// LDS=0 removes the occupancy cap; launch_bounds(256,6) keeps VGPR <= ~85.
// XCD-chunked block swizzle kept (R4: -63 MB FETCH).
// ---------------------------------------------------------------------------
__global__ __launch_bounds__(256, 6) void gather_nhwc_half_kernel(
    const _Float16* __restrict__ ws,
    const float* __restrict__ flow,
    const float* __restrict__ residual,
    float* __restrict__ out)
{
    // bijective XCD-chunk swizzle (4096 blocks, 8 XCDs, 512 per chunk)
    const int orig = blockIdx.x;
    const int idx  = (orig & 7) * 512 + (orig >> 3);

    const int b    = idx >> 10;
    const int h    = (idx >> 1) & (Hdim - 1);
    const int w0   = (idx & 1) << 8;
    const int t    = threadIdx.x;

    // ---- Phase 1: per-pixel sampling math -> registers (numerics = R0) ----
    int   offs[4];
    float wts[4];
    {
        const int w = w0 + t;
        const int pixg = h * Wdim + w;
        const float fx = flow[((size_t)b * 2 + 0) * HWdim + pixg];
        const float fy = flow[((size_t)b * 2 + 1) * HWdim + pixg];

        float gx = ((float)w + 0.5f) * (2.0f / (float)Wdim) - 1.0f + fx;
        float gy = ((float)h + 0.5f) * (2.0f / (float)Hdim) - 1.0f + fy;

        float tm = fmodf(gx + 1.0f, 2.0f);
        if (tm < 0.0f) tm += 2.0f;
        gx = tm - 1.0f;

        const float real_x = (gx + 1.0f) * ((float)Wdim * 0.5f) - 0.5f;
        const float real_y = (gy + 1.0f) * ((float)Hdim * 0.5f) - 0.5f;

        const float x0f = floorf(real_x);
        const float y0f = floorf(real_y);
        const float dx = real_x - x0f;
        const float dy = real_y - y0f;

        const int ix0 = (int)x0f;
        const int iy0 = (int)y0f;
        const int ix1 = ix0 + 1;
        const int iy1 = iy0 + 1;

        const bool vx0 = (ix0 >= 0) && (ix0 < Wdim);
        const bool vx1 = (ix1 >= 0) && (ix1 < Wdim);
        const bool vy0 = (iy0 >= 0) && (iy0 < Hdim);
        const bool vy1 = (iy1 >= 0) && (iy1 < Hdim);

        const int cx0 = min(max(ix0, 0), Wdim - 1);
        const int cx1 = min(max(ix1, 0), Wdim - 1);
        const int cy0 = min(max(iy0, 0), Hdim - 1);
        const int cy1 = min(max(iy1, 0), Hdim - 1);

        float w_tl = (1.0f - dx) * (1.0f - dy);
        float w_tr = dx * (1.0f - dy);
        float w_bl = (1.0f - dx) * dy;
        float w_br = dx * dy;
        if (!(vx0 && vy0)) w_tl = 0.0f;
        if (!(vx1 && vy0)) w_tr = 0.0f;
        if (!(vx0 && vy1)) w_bl = 0.0f;
        if (!(vx1 && vy1)) w_br = 0.0f;

        offs[0] = (cy0 * Wdim + cx0) * Cdim;   // offsets in halves
        offs[1] = (cy0 * Wdim + cx1) * Cdim;
        offs[2] = (cy1 * Wdim + cx0) * Cdim;
        offs[3] = (cy1 * Wdim + cx1) * Cdim;
        wts[0] = w_tl; wts[1] = w_tr; wts[2] = w_bl; wts[3] = w_br;
    }

    // ---- Phase 2: per-lane gather of all 32 channels, fp32 accumulate ----
    const _Float16* xb = ws + (size_t)b * (size_t)HWdim * Cdim;

    float acc[Cdim];
    #pragma unroll
    for (int k = 0; k < Cdim; ++k) acc[k] = 0.0f;

    #pragma unroll
    for (int c = 0; c < 4; ++c) {
        const _Float16* cp = xb + offs[c];
        const float wc = wts[c];
        #pragma unroll
        for (int g = 0; g < 4; ++g) {
            const f16x8 u = *(const f16x8*)(cp + g * 8);   // 16B load
            #pragma unroll
            for (int e = 0; e < 8; ++e)
                acc[g * 8 + e] += wc * (float)u[e];
        }
    }

    // ---- Phase 3: residual add + coalesced NCHW NT stores (256B runs) ----
    {
        const size_t pbase = (size_t)h * Wdim + w0 + t;
        #pragma unroll
        for (int cc = 0; cc < Cdim; ++cc) {
            const size_t gi = ((size_t)b * Cdim + cc) * HWdim + pbase;
            const float r = __builtin_nontemporal_load(residual + gi);
            __builtin_nontemporal_store(acc[cc] + r, out + gi);
        }
    }
}

// ---------------------------------------------------------------------------
// Fallback (R1 kernel) if workspace is too small for the NHWC fp16 buffer
// ---------------------------------------------------------------------------
__global__ __launch_bounds__(256) void warp_add_kernel(
    const float* __restrict__ x,
    const float* __restrict__ flow,
    const float* __restrict__ residual,
    float* __restrict__ out)
{
    int tid = blockIdx.x * blockDim.x + threadIdx.x;
    int w = tid & (Wdim - 1);
    int h = (tid >> 9) & (Hdim - 1);
    int b = tid >> 18;

    const float fx = flow[((size_t)b * 2 + 0) * HWdim + h * Wdim + w];
    const float fy = flow[((size_t)b * 2 + 1) * HWdim + h * Wdim + w];

    float gx = ((float)w + 0.5f) * (2.0f / (float)Wdim) - 1.0f + fx;
    float gy = ((float)h + 0.5f) * (2.0f / (float)Hdim) - 1.0f + fy;
    {
        float t2 = fmodf(gx + 1.0f, 2.0f);
        if (t2 < 0.0f) t2 += 2.0f;
        gx = t2 - 1.0f;
    }
    const float real_x = (gx + 1.0f) * ((float)Wdim * 0.5f) - 0.5f;
    const float real_y = (gy + 1.0f) * ((float)Hdim * 0.5f) - 0.5f;
    const float x0f = floorf(real_x);
    const float y0f = floorf(real_y);
    const float dx = real_x - x0f;
    const float dy = real_y - y0f;
    const int ix0 = (int)x0f, iy0 = (int)y0f;
    const int ix1 = ix0 + 1,  iy1 = iy0 + 1;
    const bool vx0 = (ix0 >= 0) && (ix0 < Wdim);
    const bool vx1 = (ix1 >= 0) && (ix1 < Wdim);
    const bool vy0 = (iy0 >= 0) && (iy0 < Hdim);
    const bool vy1 = (iy1 >= 0) && (iy1 < Hdim);
    const int cx0 = min(max(ix0, 0), Wdim - 1);
    const int cx1 = min(max(ix1, 0), Wdim - 1);
    const int cy0 = min(max(iy0, 0), Hdim - 1);
    const int cy1 = min(max(iy1, 0), Hdim - 1);
    float w_tl = (1.0f - dx) * (1.0f - dy);
    float w_tr = dx * (1.0f - dy);
    float w_bl = (1.0f - dx) * dy;
    float w_br = dx * dy;
    if (!(vx0 && vy0)) w_tl = 0.0f;
    if (!(vx1 && vy0)) w_tr = 0.0f;
    if (!(vx0 && vy1)) w_bl = 0.0f;
    if (!(vx1 && vy1)) w_br = 0.0f;
    const int off_tl = cy0 * Wdim + cx0;
    const int off_tr = cy0 * Wdim + cx1;
    const int off_bl = cy1 * Wdim + cx0;
    const int off_br = cy1 * Wdim + cx1;
    const size_t base = (size_t)b * Cdim * HWdim;
    const int    pix  = h * Wdim + w;
    const float* xb = x + base;
    const float* rbp = residual + base + pix;
    float*       ob = out + base + pix;
    #pragma unroll 8
    for (int c = 0; c < Cdim; ++c) {
        const float* xc = xb + (size_t)c * HWdim;
        float v = w_tl * xc[off_tl] + w_tr * xc[off_tr]
                + w_bl * xc[off_bl] + w_br * xc[off_br]
                + rbp[(size_t)c * HWdim];
        ob[(size_t)c * HWdim] = v;
    }
}

extern "C" void kernel_launch(void* const* d_in, const int* in_sizes, int n_in,
                              void* d_out, int out_size, void* d_ws, size_t ws_size,
                              hipStream_t stream) {
    const float* x        = (const float*)d_in[0];
    const float* flow     = (const float*)d_in[1];
    const float* residual = (const float*)d_in[2];
    float* out            = (float*)d_out;

    const size_t ws_needed = (size_t)Bdim * Cdim * HWdim * sizeof(_Float16); // 64 MiB

    if (ws_size >= ws_needed) {
        _Float16* ws = (_Float16*)d_ws;
        transpose_nhwc_half_kernel<<<Bdim * Hdim * (Wdim / 128), 256, 0, stream>>>(x, ws);
        gather_nhwc_half_kernel<<<Bdim * Hdim * Wdim / 256, 256, 0, stream>>>(ws, flow, residual, out);
    } else {
        const int total = Bdim * Hdim * Wdim;
        warp_add_kernel<<<total / 256, 256, 0, stream>>>(x, flow, residual, out);
    }
}

// Round 8
// 351.476 us; speedup vs baseline: 1.1305x; 1.1305x over previous
//
#include <hip/hip_runtime.h>

// Problem constants (match reference)
#define Bdim 4
#define Cdim 32
#define Hdim 512
#define Wdim 512
#define HWdim (Hdim * Wdim)

typedef __attribute__((ext_vector_type(4))) float    f32x4;
typedef __attribute__((ext_vector_type(2))) _Float16 f16x2;
typedef __attribute__((ext_vector_type(4))) _Float16 f16x4;
typedef __attribute__((ext_vector_type(8))) _Float16 f16x8;

// ---------------------------------------------------------------------------
// Kernel A: transpose x [B][C][H][W] (fp32) -> ws NHWC [B][H][W][C] (fp16)
// One block: (b, h) fixed, 128-wide w strip, all 32 c.
// XCD-chunk swizzle aligned with the gather kernel (ws stays in writer's L2).
// ---------------------------------------------------------------------------
__global__ __launch_bounds__(256) void transpose_nhwc_half_kernel(
    const float* __restrict__ x, _Float16* __restrict__ ws)
{
    __shared__ float lds[Cdim * 132];   // 32 x 132 floats = 16896 B

    // 8192 blocks; chunk swizzle: XCD k owns idx [k*1024, (k+1)*1024)
    const int orig = blockIdx.x;
    const int idx  = (orig & 7) * 1024 + (orig >> 3);

    const int tw  = idx & 3;                  // W/128 = 4 strips
    const int h   = (idx >> 2) & (Hdim - 1);
    const int b   = idx >> 11;
    const int w0  = tw * 128;
    const int t   = threadIdx.x;

    // 32c x 128w = 1024 float4s, 4 per thread. Issue all loads first (MLP).
    f32x4 r[4];
    #pragma unroll
    for (int i = 0; i < 4; ++i) {
        const int f4 = i * 256 + t;           // 0..1023
        const int c  = f4 >> 5;               // 32 float4 per row
        const int w4 = f4 & 31;
        r[i] = *(const f32x4*)(x + (((size_t)b * Cdim + c) * Hdim + h) * Wdim + w0 + w4 * 4);
    }
    #pragma unroll
    for (int i = 0; i < 4; ++i) {
        const int f4 = i * 256 + t;
        *(f32x4*)(lds + (f4 >> 5) * 132 + (f4 & 31) * 4) = r[i];
    }
    __syncthreads();

    // output block = 4096 halves contiguous; thread t writes halves [t*16, t*16+16)
    const size_t base = (((size_t)b * Hdim + h) * Wdim + w0) * Cdim;
    const int w_ = t >> 1;                    // local w (0..127)
    const int c0 = (t & 1) * 16;              // first channel (0 or 16)
    f16x8 v0, v1;
    #pragma unroll
    for (int k = 0; k < 8; ++k) v0[k] = (_Float16)lds[(c0 + k) * 132 + w_];
    #pragma unroll
    for (int k = 0; k < 8; ++k) v1[k] = (_Float16)lds[(c0 + 8 + k) * 132 + w_];
    *(f16x8*)(ws + base + (size_t)w_ * Cdim + c0)     = v0;   // 16B store
    *(f16x8*)(ws + base + (size_t)w_ * Cdim + c0 + 8) = v1;   // 16B store
}

// ---------------------------------------------------------------------------
// Kernel B: gather from NHWC fp16 ws + residual -> out (NCHW fp32)
// R8 = R5/R6 wave-cooperative structure (proven 77.4 us: 4 lanes/corner-line,
// zero __syncthreads, wave-owns-64-pixels) + RESIDUAL HOIST:
//   all 32 residual NT loads issued right after the flow loads (addresses
//   depend only on t), pinned above phase 2 with sched_barrier(0) so the
//   streaming HBM fetch overlaps the entire scattered-gather phase instead
//   of being serialized after the wave-internal join (R6: phase-3 residual
//   reads sat behind all ws gathers). Issue order flow->residual->corners;
//   in-order vmcnt retirement gives residuals a full phase-1 head start.
// ---------------------------------------------------------------------------
__global__ __launch_bounds__(256, 5) void gather_nhwc_half_kernel(
    const _Float16* __restrict__ ws,
    const float* __restrict__ flow,
    const float* __restrict__ residual,
    float* __restrict__ out)
{
    __shared__ _Float16 s_buf[4 * 64 * 34];   // 17408 B, 4 disjoint per-wave regions

    // bijective XCD-chunk swizzle (4096 blocks, 8 XCDs, 512 per chunk)
    const int orig = blockIdx.x;
    const int idx  = (orig & 7) * 512 + (orig >> 3);

    const int b    = idx >> 10;
    const int h    = (idx >> 1) & (Hdim - 1);
    const int w0   = (idx & 1) << 8;
    const int t    = threadIdx.x;
    const int lane = t & 63;
    const int wv   = t >> 6;

    const size_t pbase = (size_t)h * Wdim + w0 + t;

    // ---- flow loads (first in vmcnt order) ----
    const float fx = flow[((size_t)b * 2 + 0) * HWdim + (size_t)h * Wdim + w0 + t];
    const float fy = flow[((size_t)b * 2 + 1) * HWdim + (size_t)h * Wdim + w0 + t];

    // ---- residual hoist: 32 NT loads issued now, consumed in phase 3 ----
    float rres[Cdim];
    {
        const float* rp = residual + (size_t)b * Cdim * (size_t)HWdim + pbase;
        #pragma unroll
        for (int cc = 0; cc < Cdim; ++cc)
            rres[cc] = __builtin_nontemporal_load(rp + (size_t)cc * HWdim);
    }
    __builtin_amdgcn_sched_barrier(0);   // pin the loads above; no waitcnt here

    // ---- Phase 1: per-pixel sampling math -> registers (numerics = R0) ----
    int   off0, off1, off2, off3;
    float wt0,  wt1,  wt2,  wt3;
    {
        const int w = w0 + t;

        float gx = ((float)w + 0.5f) * (2.0f / (float)Wdim) - 1.0f + fx;
        float gy = ((float)h + 0.5f) * (2.0f / (float)Hdim) - 1.0f + fy;

        float tm = fmodf(gx + 1.0f, 2.0f);
        if (tm < 0.0f) tm += 2.0f;
        gx = tm - 1.0f;

        const float real_x = (gx + 1.0f) * ((float)Wdim * 0.5f) - 0.5f;
        const float real_y = (gy + 1.0f) * ((float)Hdim * 0.5f) - 0.5f;

        const float x0f = floorf(real_x);
        const float y0f = floorf(real_y);
        const float dx = real_x - x0f;
        const float dy = real_y - y0f;

        const int ix0 = (int)x0f;
        const int iy0 = (int)y0f;
        const int ix1 = ix0 + 1;
        const int iy1 = iy0 + 1;

        const bool vx0 = (ix0 >= 0) && (ix0 < Wdim);
        const bool vx1 = (ix1 >= 0) && (ix1 < Wdim);
        const bool vy0 = (iy0 >= 0) && (iy0 < Hdim);
        const bool vy1 = (iy1 >= 0) && (iy1 < Hdim);

        const int cx0 = min(max(ix0, 0), Wdim - 1);
        const int cx1 = min(max(ix1, 0), Wdim - 1);
        const int cy0 = min(max(iy0, 0), Hdim - 1);
        const int cy1 = min(max(iy1, 0), Hdim - 1);

        float w_tl = (1.0f - dx) * (1.0f - dy);
        float w_tr = dx * (1.0f - dy);
        float w_bl = (1.0f - dx) * dy;
        float w_br = dx * dy;
        if (!(vx0 && vy0)) w_tl = 0.0f;
        if (!(vx1 && vy0)) w_tr = 0.0f;
        if (!(vx0 && vy1)) w_bl = 0.0f;
        if (!(vx1 && vy1)) w_br = 0.0f;

        off0 = (cy0 * Wdim + cx0) * Cdim;   // offsets in halves
        off1 = (cy0 * Wdim + cx1) * Cdim;
        off2 = (cy1 * Wdim + cx0) * Cdim;
        off3 = (cy1 * Wdim + cx1) * Cdim;
        wt0 = w_tl; wt1 = w_tr; wt2 = w_bl; wt3 = w_br;
    }

    // ---- Phase 2: wave-local channel-major gather, 2-deep pipeline ----
    {
        const int ci = lane & 3;            // channel oct: channels 8ci..8ci+7
        const int c0 = ci * 8;
        const int ps = lane >> 2;           // pixel slot within pass (0..15)
        const _Float16* xb = ws + (size_t)b * (size_t)HWdim * Cdim + c0;
        _Float16* sb = s_buf + wv * (64 * 34);

        f16x8 cv[4];
        {
            const int sj = ps;              // pass 0 source lane (wave-relative)
            const int o0 = __shfl(off0, sj, 64);
            const int o1 = __shfl(off1, sj, 64);
            const int o2 = __shfl(off2, sj, 64);
            const int o3 = __shfl(off3, sj, 64);
            cv[0] = *(const f16x8*)(xb + o0);   // 16B load, 4 lanes = 64B line
            cv[1] = *(const f16x8*)(xb + o1);
            cv[2] = *(const f16x8*)(xb + o2);
            cv[3] = *(const f16x8*)(xb + o3);
        }

        #pragma unroll
        for (int j = 0; j < 4; ++j) {
            f16x8 nv[4];
            if (j < 3) {                     // prefetch pass j+1
                const int sj = (j + 1) * 16 + ps;
                const int o0 = __shfl(off0, sj, 64);
                const int o1 = __shfl(off1, sj, 64);
                const int o2 = __shfl(off2, sj, 64);
                const int o3 = __shfl(off3, sj, 64);
                nv[0] = *(const f16x8*)(xb + o0);
                nv[1] = *(const f16x8*)(xb + o1);
                nv[2] = *(const f16x8*)(xb + o2);
                nv[3] = *(const f16x8*)(xb + o3);
            }

            const int sj = j * 16 + ps;      // consume pass j
            const float w0_ = __shfl(wt0, sj, 64);
            const float w1_ = __shfl(wt1, sj, 64);
            const float w2_ = __shfl(wt2, sj, 64);
            const float w3_ = __shfl(wt3, sj, 64);
            const int lpix = sj;             // 0..63 within wave region

            #pragma unroll
            for (int q = 0; q < 4; ++q) {    // channel pairs within oct
                const float a0 = w0_ * (float)cv[0][2*q]   + w1_ * (float)cv[1][2*q]
                               + w2_ * (float)cv[2][2*q]   + w3_ * (float)cv[3][2*q];
                const float a1 = w0_ * (float)cv[0][2*q+1] + w1_ * (float)cv[1][2*q+1]
                               + w2_ * (float)cv[2][2*q+1] + w3_ * (float)cv[3][2*q+1];
                f16x2 hp; hp[0] = (_Float16)a0; hp[1] = (_Float16)a1;
                *(f16x2*)(sb + lpix * 34 + c0 + 2*q) = hp;   // 4B LDS store
            }

            if (j < 3) {
                cv[0] = nv[0]; cv[1] = nv[1]; cv[2] = nv[2]; cv[3] = nv[3];
            }
        }
    }

    // wave-internal ordering: all DS writes visible before DS reads (no barrier)
    __builtin_amdgcn_wave_barrier();
    asm volatile("s_waitcnt lgkmcnt(0)" ::: "memory");
    __builtin_amdgcn_sched_barrier(0);

    // ---- Phase 3: lane owns its pixel; register residual + NCHW NT stores ----
    {
        const _Float16* row = s_buf + wv * (64 * 34) + lane * 34;
        #pragma unroll
        for (int g = 0; g < 4; ++g) {        // channel oct per group
            const int cc = g * 8;
            const f16x2 v0 = *(const f16x2*)(row + cc);
            const f16x2 v1 = *(const f16x2*)(row + cc + 2);
            const f16x2 v2 = *(const f16x2*)(row + cc + 4);
            const f16x2 v3 = *(const f16x2*)(row + cc + 6);
            const size_t gi = ((size_t)b * Cdim + cc) * HWdim + pbase;
            __builtin_nontemporal_store((float)v0[0] + rres[cc],     out + gi);
            __builtin_nontemporal_store((float)v0[1] + rres[cc + 1], out + gi + (size_t)HWdim);
            __builtin_nontemporal_store((float)v1[0] + rres[cc + 2], out + gi + (size_t)(2 * HWdim));
            __builtin_nontemporal_store((float)v1[1] + rres[cc + 3], out + gi + (size_t)(3 * HWdim));
            __builtin_nontemporal_store((float)v2[0] + rres[cc + 4], out + gi + (size_t)(4 * HWdim));
            __builtin_nontemporal_store((float)v2[1] + rres[cc + 5], out + gi + (size_t)(5 * HWdim));
            __builtin_nontemporal_store((float)v3[0] + rres[cc + 6], out + gi + (size_t)(6 * HWdim));
            __builtin_nontemporal_store((float)v3[1] + rres[cc + 7], out + gi + (size_t)(7 * HWdim));
        }
    }
}

// ---------------------------------------------------------------------------
// Fallback (R1 kernel) if workspace is too small for the NHWC fp16 buffer
// ---------------------------------------------------------------------------
__global__ __launch_bounds__(256) void warp_add_kernel(
    const float* __restrict__ x,
    const float* __restrict__ flow,
    const float* __restrict__ residual,
    float* __restrict__ out)
{
    int tid = blockIdx.x * blockDim.x + threadIdx.x;
    int w = tid & (Wdim - 1);
    int h = (tid >> 9) & (Hdim - 1);
    int b = tid >> 18;

    const float fx = flow[((size_t)b * 2 + 0) * HWdim + h * Wdim + w];
    const float fy = flow[((size_t)b * 2 + 1) * HWdim + h * Wdim + w];

    float gx = ((float)w + 0.5f) * (2.0f / (float)Wdim) - 1.0f + fx;
    float gy = ((float)h + 0.5f) * (2.0f / (float)Hdim) - 1.0f + fy;
    {
        float t2 = fmodf(gx + 1.0f, 2.0f);
        if (t2 < 0.0f) t2 += 2.0f;
        gx = t2 - 1.0f;
    }
    const float real_x = (gx + 1.0f) * ((float)Wdim * 0.5f) - 0.5f;
    const float real_y = (gy + 1.0f) * ((float)Hdim * 0.5f) - 0.5f;
    const float x0f = floorf(real_x);
    const float y0f = floorf(real_y);
    const float dx = real_x - x0f;
    const float dy = real_y - y0f;
    const int ix0 = (int)x0f, iy0 = (int)y0f;
    const int ix1 = ix0 + 1,  iy1 = iy0 + 1;
    const bool vx0 = (ix0 >= 0) && (ix0 < Wdim);
    const bool vx1 = (ix1 >= 0) && (ix1 < Wdim);
    const bool vy0 = (iy0 >= 0) && (iy0 < Hdim);
    const bool vy1 = (iy1 >= 0) && (iy1 < Hdim);
    const int cx0 = min(max(ix0, 0), Wdim - 1);
    const int cx1 = min(max(ix1, 0), Wdim - 1);
    const int cy0 = min(max(iy0, 0), Hdim - 1);
    const int cy1 = min(max(iy1, 0), Hdim - 1);
    float w_tl = (1.0f - dx) * (1.0f - dy);
    float w_tr = dx * (1.0f - dy);
    float w_bl = (1.0f - dx) * dy;
    float w_br = dx * dy;
    if (!(vx0 && vy0)) w_tl = 0.0f;
    if (!(vx1 && vy0)) w_tr = 0.0f;
    if (!(vx0 && vy1)) w_bl = 0.0f;
    if (!(vx1 && vy1)) w_br = 0.0f;
    const int off_tl = cy0 * Wdim + cx0;
    const int off_tr = cy0 * Wdim + cx1;
    const int off_bl = cy1 * Wdim + cx0;
    const int off_br = cy1 * Wdim + cx1;
    const size_t base = (size_t)b * Cdim * HWdim;
    const int    pix  = h * Wdim + w;
    const float* xb = x + base;
    const float* rbp = residual + base + pix;
    float*       ob = out + base + pix;
    #pragma unroll 8
    for (int c = 0; c < Cdim; ++c) {
        const float* xc = xb + (size_t)c * HWdim;
        float v = w_tl * xc[off_tl] + w_tr * xc[off_tr]
                + w_bl * xc[off_bl] + w_br * xc[off_br]
                + rbp[(size_t)c * HWdim];
        ob[(size_t)c * HWdim] = v;
    }
}

extern "C" void kernel_launch(void* const* d_in, const int* in_sizes, int n_in,
                              void* d_out, int out_size, void* d_ws, size_t ws_size,
                              hipStream_t stream) {
    const float* x        = (const float*)d_in[0];
    const float* flow     = (const float*)d_in[1];
    const float* residual = (const float*)d_in[2];
    float* out            = (float*)d_out;

    const size_t ws_needed = (size_t)Bdim * Cdim * HWdim * sizeof(_Float16); // 64 MiB

    if (ws_size >= ws_needed) {
        _Float16* ws = (_Float16*)d_ws;
        transpose_nhwc_half_kernel<<<Bdim * Hdim * (Wdim / 128), 256, 0, stream>>>(x, ws);
        gather_nhwc_half_kernel<<<Bdim * Hdim * Wdim / 256, 256, 0, stream>>>(ws, flow, residual, out);
    } else {
        const int total = Bdim * Hdim * Wdim;
        warp_add_kernel<<<total / 256, 256, 0, stream>>>(x, flow, residual, out);
    }
}

// Round 9
// 337.398 us; speedup vs baseline: 1.1777x; 1.0417x over previous
//
#include <hip/hip_runtime.h>

// Problem constants (match reference)
#define Bdim 4
#define Cdim 32
#define Hdim 512
#define Wdim 512
#define HWdim (Hdim * Wdim)

typedef __attribute__((ext_vector_type(4))) float    f32x4;
typedef __attribute__((ext_vector_type(2))) _Float16 f16x2;
typedef __attribute__((ext_vector_type(4))) _Float16 f16x4;
typedef __attribute__((ext_vector_type(8))) _Float16 f16x8;

// ---------------------------------------------------------------------------
// Kernel A: transpose x [B][C][H][W] (fp32) -> ws NHWC [B][H][W][C] (fp16)
// One block: (b, h) fixed, 128-wide w strip, all 32 c.
// R9: x loads are NONTEMPORAL (stream-once; keep L2 free for the ws lines
// being written, which the gather immediately re-reads - R4 showed ws L2
// residency is worth 63 MB of FETCH). ws stores stay normal (L2-allocate).
// XCD-chunk swizzle aligned with the gather kernel.
// ---------------------------------------------------------------------------
__global__ __launch_bounds__(256) void transpose_nhwc_half_kernel(
    const float* __restrict__ x, _Float16* __restrict__ ws)
{
    __shared__ float lds[Cdim * 132];   // 32 x 132 floats = 16896 B

    // 8192 blocks; chunk swizzle: XCD k owns idx [k*1024, (k+1)*1024)
    const int orig = blockIdx.x;
    const int idx  = (orig & 7) * 1024 + (orig >> 3);

    const int tw  = idx & 3;                  // W/128 = 4 strips
    const int h   = (idx >> 2) & (Hdim - 1);
    const int b   = idx >> 11;
    const int w0  = tw * 128;
    const int t   = threadIdx.x;

    // 32c x 128w = 1024 float4s, 4 per thread. Issue all loads first (MLP).
    f32x4 r[4];
    #pragma unroll
    for (int i = 0; i < 4; ++i) {
        const int f4 = i * 256 + t;           // 0..1023
        const int c  = f4 >> 5;               // 32 float4 per row
        const int w4 = f4 & 31;
        r[i] = __builtin_nontemporal_load(
            (const f32x4*)(x + (((size_t)b * Cdim + c) * Hdim + h) * Wdim + w0 + w4 * 4));
    }
    #pragma unroll
    for (int i = 0; i < 4; ++i) {
        const int f4 = i * 256 + t;
        *(f32x4*)(lds + (f4 >> 5) * 132 + (f4 & 31) * 4) = r[i];
    }
    __syncthreads();

    // output block = 4096 halves contiguous; thread t writes halves [t*16, t*16+16)
    const size_t base = (((size_t)b * Hdim + h) * Wdim + w0) * Cdim;
    const int w_ = t >> 1;                    // local w (0..127)
    const int c0 = (t & 1) * 16;              // first channel (0 or 16)
    f16x8 v0, v1;
    #pragma unroll
    for (int k = 0; k < 8; ++k) v0[k] = (_Float16)lds[(c0 + k) * 132 + w_];
    #pragma unroll
    for (int k = 0; k < 8; ++k) v1[k] = (_Float16)lds[(c0 + 8 + k) * 132 + w_];
    *(f16x8*)(ws + base + (size_t)w_ * Cdim + c0)     = v0;   // 16B store
    *(f16x8*)(ws + base + (size_t)w_ * Cdim + c0 + 8) = v1;   // 16B store
}

// ---------------------------------------------------------------------------
// Kernel B: gather from NHWC fp16 ws + residual -> out (NCHW fp32)
// R6-EXACT REVERT (best measured: 77.4 us). Wave owns 64 pixels, zero
// __syncthreads, 4 lanes share each 64B corner line (f16x8 loads), all 16
// corner loads issued upfront, fp16 pack into per-wave s_buf, wave-internal
// lgkmcnt join, phase-3 inline NT residual + NT NCHW stores (256B runs).
// XCD-chunked block swizzle (R4: -63 MB FETCH).
// ---------------------------------------------------------------------------
__global__ __launch_bounds__(256, 5) void gather_nhwc_half_kernel(
    const _Float16* __restrict__ ws,
    const float* __restrict__ flow,
    const float* __restrict__ residual,
    float* __restrict__ out)
{
    __shared__ _Float16 s_buf[4 * 64 * 34];   // 17408 B, 4 disjoint per-wave regions

    // bijective XCD-chunk swizzle (4096 blocks, 8 XCDs, 512 per chunk)
    const int orig = blockIdx.x;
    const int idx  = (orig & 7) * 512 + (orig >> 3);

    const int b    = idx >> 10;
    const int h    = (idx >> 1) & (Hdim - 1);
    const int w0   = (idx & 1) << 8;
    const int t    = threadIdx.x;
    const int lane = t & 63;
    const int wv   = t >> 6;

    // ---- Phase 1: per-pixel sampling math -> registers (numerics = R0) ----
    int   off0, off1, off2, off3;
    float wt0,  wt1,  wt2,  wt3;
    {
        const int w = w0 + t;
        const int pixg = h * Wdim + w;
        const float fx = flow[((size_t)b * 2 + 0) * HWdim + pixg];
        const float fy = flow[((size_t)b * 2 + 1) * HWdim + pixg];

        float gx = ((float)w + 0.5f) * (2.0f / (float)Wdim) - 1.0f + fx;
        float gy = ((float)h + 0.5f) * (2.0f / (float)Hdim) - 1.0f + fy;

        float tm = fmodf(gx + 1.0f, 2.0f);
        if (tm < 0.0f) tm += 2.0f;
        gx = tm - 1.0f;

        const float real_x = (gx + 1.0f) * ((float)Wdim * 0.5f) - 0.5f;
        const float real_y = (gy + 1.0f) * ((float)Hdim * 0.5f) - 0.5f;

        const float x0f = floorf(real_x);
        const float y0f = floorf(real_y);
        const float dx = real_x - x0f;
        const float dy = real_y - y0f;

        const int ix0 = (int)x0f;
        const int iy0 = (int)y0f;
        const int ix1 = ix0 + 1;
        const int iy1 = iy0 + 1;

        const bool vx0 = (ix0 >= 0) && (ix0 < Wdim);
        const bool vx1 = (ix1 >= 0) && (ix1 < Wdim);
        const bool vy0 = (iy0 >= 0) && (iy0 < Hdim);
        const bool vy1 = (iy1 >= 0) && (iy1 < Hdim);

        const int cx0 = min(max(ix0, 0), Wdim - 1);
        const int cx1 = min(max(ix1, 0), Wdim - 1);
        const int cy0 = min(max(iy0, 0), Hdim - 1);
        const int cy1 = min(max(iy1, 0), Hdim - 1);

        float w_tl = (1.0f - dx) * (1.0f - dy);
        float w_tr = dx * (1.0f - dy);
        float w_bl = (1.0f - dx) * dy;
        float w_br = dx * dy;
        if (!(vx0 && vy0)) w_tl = 0.0f;
        if (!(vx1 && vy0)) w_tr = 0.0f;
        if (!(vx0 && vy1)) w_bl = 0.0f;
        if (!(vx1 && vy1)) w_br = 0.0f;

        off0 = (cy0 * Wdim + cx0) * Cdim;   // offsets in halves
        off1 = (cy0 * Wdim + cx1) * Cdim;
        off2 = (cy1 * Wdim + cx0) * Cdim;
        off3 = (cy1 * Wdim + cx1) * Cdim;
        wt0 = w_tl; wt1 = w_tr; wt2 = w_bl; wt3 = w_br;
    }

    // ---- Phase 2: wave-local channel-major gather, ALL loads upfront ----
    {
        const int ci = lane & 3;            // channel oct: channels 8ci..8ci+7
        const int c0 = ci * 8;
        const int ps = lane >> 2;           // pixel slot within pass (0..15)
        const _Float16* xb = ws + (size_t)b * (size_t)HWdim * Cdim + c0;
        _Float16* sb = s_buf + wv * (64 * 34);

        // issue all 16 corner loads (4 passes x 4 corners), 256 B/lane in flight
        f16x8 cv0[4], cv1[4], cv2[4], cv3[4];
        #pragma unroll
        for (int j = 0; j < 4; ++j) {
            const int sj = j * 16 + ps;
            const int o0 = __shfl(off0, sj, 64);
            const int o1 = __shfl(off1, sj, 64);
            const int o2 = __shfl(off2, sj, 64);
            const int o3 = __shfl(off3, sj, 64);
            f16x8* cv = (j == 0) ? cv0 : (j == 1) ? cv1 : (j == 2) ? cv2 : cv3;
            cv[0] = *(const f16x8*)(xb + o0);   // 16B load, 4 lanes = 64B line
            cv[1] = *(const f16x8*)(xb + o1);
            cv[2] = *(const f16x8*)(xb + o2);
            cv[3] = *(const f16x8*)(xb + o3);
        }

        // consume passes in order; compiler inserts vmcnt(12)/(8)/(4)/(0)
        #pragma unroll
        for (int j = 0; j < 4; ++j) {
            const f16x8* cv = (j == 0) ? cv0 : (j == 1) ? cv1 : (j == 2) ? cv2 : cv3;
            const int sj = j * 16 + ps;
            const float w0_ = __shfl(wt0, sj, 64);
            const float w1_ = __shfl(wt1, sj, 64);
            const float w2_ = __shfl(wt2, sj, 64);
            const float w3_ = __shfl(wt3, sj, 64);
            const int lpix = sj;             // 0..63 within wave region

            #pragma unroll
            for (int q = 0; q < 4; ++q) {    // channel pairs within oct
                const float a0 = w0_ * (float)cv[0][2*q]   + w1_ * (float)cv[1][2*q]
                               + w2_ * (float)cv[2][2*q]   + w3_ * (float)cv[3][2*q];
                const float a1 = w0_ * (float)cv[0][2*q+1] + w1_ * (float)cv[1][2*q+1]
                               + w2_ * (float)cv[2][2*q+1] + w3_ * (float)cv[3][2*q+1];
                f16x2 hp; hp[0] = (_Float16)a0; hp[1] = (_Float16)a1;
                *(f16x2*)(sb + lpix * 34 + c0 + 2*q) = hp;   // 4B LDS store
            }
        }
    }

    // wave-internal ordering: all DS writes visible before DS reads (no barrier)
    __builtin_amdgcn_wave_barrier();
    asm volatile("s_waitcnt lgkmcnt(0)" ::: "memory");
    __builtin_amdgcn_sched_barrier(0);

    // ---- Phase 3: lane owns its pixel; coalesced NCHW store + residual ----
    {
        const size_t pbase = (size_t)h * Wdim + w0 + t;
        const _Float16* row = s_buf + wv * (64 * 34) + lane * 34;
        #pragma unroll
        for (int g = 0; g < 4; ++g) {        // channel oct per group
            const int cc = g * 8;
            const f16x2 v0 = *(const f16x2*)(row + cc);
            const f16x2 v1 = *(const f16x2*)(row + cc + 2);
            const f16x2 v2 = *(const f16x2*)(row + cc + 4);
            const f16x2 v3 = *(const f16x2*)(row + cc + 6);
            const size_t gi = ((size_t)b * Cdim + cc) * HWdim + pbase;
            const float r0 = __builtin_nontemporal_load(residual + gi);
            const float r1 = __builtin_nontemporal_load(residual + gi + (size_t)HWdim);
            const float r2 = __builtin_nontemporal_load(residual + gi + (size_t)(2 * HWdim));
            const float r3 = __builtin_nontemporal_load(residual + gi + (size_t)(3 * HWdim));
            const float r4 = __builtin_nontemporal_load(residual + gi + (size_t)(4 * HWdim));
            const float r5 = __builtin_nontemporal_load(residual + gi + (size_t)(5 * HWdim));
            const float r6 = __builtin_nontemporal_load(residual + gi + (size_t)(6 * HWdim));
            const float r7 = __builtin_nontemporal_load(residual + gi + (size_t)(7 * HWdim));
            __builtin_nontemporal_store((float)v0[0] + r0, out + gi);
            __builtin_nontemporal_store((float)v0[1] + r1, out + gi + (size_t)HWdim);
            __builtin_nontemporal_store((float)v1[0] + r2, out + gi + (size_t)(2 * HWdim));
            __builtin_nontemporal_store((float)v1[1] + r3, out + gi + (size_t)(3 * HWdim));
            __builtin_nontemporal_store((float)v2[0] + r4, out + gi + (size_t)(4 * HWdim));
            __builtin_nontemporal_store((float)v2[1] + r5, out + gi + (size_t)(5 * HWdim));
            __builtin_nontemporal_store((float)v3[0] + r6, out + gi + (size_t)(6 * HWdim));
            __builtin_nontemporal_store((float)v3[1] + r7, out + gi + (size_t)(7 * HWdim));
        }
    }
}

// ---------------------------------------------------------------------------
// Fallback (R1 kernel) if workspace is too small for the NHWC fp16 buffer
// ---------------------------------------------------------------------------
__global__ __launch_bounds__(256) void warp_add_kernel(
    const float* __restrict__ x,
    const float* __restrict__ flow,
    const float* __restrict__ residual,
    float* __restrict__ out)
{
    int tid = blockIdx.x * blockDim.x + threadIdx.x;
    int w = tid & (Wdim - 1);
    int h = (tid >> 9) & (Hdim - 1);
    int b = tid >> 18;

    const float fx = flow[((size_t)b * 2 + 0) * HWdim + h * Wdim + w];
    const float fy = flow[((size_t)b * 2 + 1) * HWdim + h * Wdim + w];

    float gx = ((float)w + 0.5f) * (2.0f / (float)Wdim) - 1.0f + fx;
    float gy = ((float)h + 0.5f) * (2.0f / (float)Hdim) - 1.0f + fy;
    {
        float t2 = fmodf(gx + 1.0f, 2.0f);
        if (t2 < 0.0f) t2 += 2.0f;
        gx = t2 - 1.0f;
    }
    const float real_x = (gx + 1.0f) * ((float)Wdim * 0.5f) - 0.5f;
    const float real_y = (gy + 1.0f) * ((float)Hdim * 0.5f) - 0.5f;
    const float x0f = floorf(real_x);
    const float y0f = floorf(real_y);
    const float dx = real_x - x0f;
    const float dy = real_y - y0f;
    const int ix0 = (int)x0f, iy0 = (int)y0f;
    const int ix1 = ix0 + 1,  iy1 = iy0 + 1;
    const bool vx0 = (ix0 >= 0) && (ix0 < Wdim);
    const bool vx1 = (ix1 >= 0) && (ix1 < Wdim);
    const bool vy0 = (iy0 >= 0) && (iy0 < Hdim);
    const bool vy1 = (iy1 >= 0) && (iy1 < Hdim);
    const int cx0 = min(max(ix0, 0), Wdim - 1);
    const int cx1 = min(max(ix1, 0), Wdim - 1);
    const int cy0 = min(max(iy0, 0), Hdim - 1);
    const int cy1 = min(max(iy1, 0), Hdim - 1);
    float w_tl = (1.0f - dx) * (1.0f - dy);
    float w_tr = dx * (1.0f - dy);
    float w_bl = (1.0f - dx) * dy;
    float w_br = dx * dy;
    if (!(vx0 && vy0)) w_tl = 0.0f;
    if (!(vx1 && vy0)) w_tr = 0.0f;
    if (!(vx0 && vy1)) w_bl = 0.0f;
    if (!(vx1 && vy1)) w_br = 0.0f;
    const int off_tl = cy0 * Wdim + cx0;
    const int off_tr = cy0 * Wdim + cx1;
    const int off_bl = cy1 * Wdim + cx0;
    const int off_br = cy1 * Wdim + cx1;
    const size_t base = (size_t)b * Cdim * HWdim;
    const int    pix  = h * Wdim + w;
    const float* xb = x + base;
    const float* rbp = residual + base + pix;
    float*       ob = out + base + pix;
    #pragma unroll 8
    for (int c = 0; c < Cdim; ++c) {
        const float* xc = xb + (size_t)c * HWdim;
        float v = w_tl * xc[off_tl] + w_tr * xc[off_tr]
                + w_bl * xc[off_bl] + w_br * xc[off_br]
                + rbp[(size_t)c * HWdim];
        ob[(size_t)c * HWdim] = v;
    }
}

extern "C" void kernel_launch(void* const* d_in, const int* in_sizes, int n_in,
                              void* d_out, int out_size, void* d_ws, size_t ws_size,
                              hipStream_t stream) {
    const float* x        = (const float*)d_in[0];
    const float* flow     = (const float*)d_in[1];
    const float* residual = (const float*)d_in[2];
    float* out            = (float*)d_out;

    const size_t ws_needed = (size_t)Bdim * Cdim * HWdim * sizeof(_Float16); // 64 MiB

    if (ws_size >= ws_needed) {
        _Float16* ws = (_Float16*)d_ws;
        transpose_nhwc_half_kernel<<<Bdim * Hdim * (Wdim / 128), 256, 0, stream>>>(x, ws);
        gather_nhwc_half_kernel<<<Bdim * Hdim * Wdim / 256, 256, 0, stream>>>(ws, flow, residual, out);
    } else {
        const int total = Bdim * Hdim * Wdim;
        warp_add_kernel<<<total / 256, 256, 0, stream>>>(x, flow, residual, out);
    }
}